// Round 4
// baseline (1793.210 us; speedup 1.0000x reference)
//
#include <hip/hip_runtime.h>
#include <math.h>

// AddrNet eval forward: B=524288, D_MODEL=128, HID=16, N_BINS=256, DEPTH=8.
// Round 4: numpy-faithful float32, NO-FMA matmuls.
// Evidence: absmax stuck at exactly 134 across f64 / f32-seqFMA / f32+np-exp
// => 1-2 flipped slots decided by matmul rounding only; ref's matmul profile
// is NOT fused. Model: translated numpy computes p_k = fl(h_k*w_kj) (separate
// mul rounding), then sequential k-ascending adds (einsum / mul+.sum(axis=1)
// semantics), bias added after. Enforced with clang fp contract(off).

constexpr int BATCH  = 524288;
constexpr int DM     = 128;
constexpr int H      = 16;
constexpr int NB     = 256;
constexpr int DEPTHN = 8;

constexpr int BLOCK = 512;

__device__ __forceinline__ float np_expf(float x) {
    // Replica of numpy's SIMD float32 exp (Cephes scheme). Uses explicit FMA
    // (numpy's vectorized path is FMA-based); unaffected by contract pragma.
    const float LOG2E = 1.442695040888963407f;
    const float C1    = 0.693359375f;
    const float C2    = -2.12194440e-4f;
    float q = rintf(x * LOG2E);
    float r = __builtin_fmaf(q, -C1, x);
    r = __builtin_fmaf(q, -C2, r);
    float p = 1.9875691500E-4f;
    p = __builtin_fmaf(p, r, 1.3981999507E-3f);
    p = __builtin_fmaf(p, r, 8.3334519073E-3f);
    p = __builtin_fmaf(p, r, 4.1665795894E-2f);
    p = __builtin_fmaf(p, r, 1.6666665459E-1f);
    p = __builtin_fmaf(p, r, 5.0000001201E-1f);
    p = __builtin_fmaf(p, r * r, r);
    p = p + 1.0f;
    if (x > 88.72283935546875f)      return INFINITY;
    if (x < -103.97208404541015625f) return 0.0f;
    return ldexpf(p, (int)q);
}

__global__ __launch_bounds__(BLOCK) void addrnet_nofma_kernel(
    const float* __restrict__ x,      // [B,128]
    const float* __restrict__ W_in,   // [128,16]
    const float* __restrict__ b_in,   // [16]
    const float* __restrict__ embed,  // [256,16]
    const float* __restrict__ W_mlp,  // [16,16]
    const float* __restrict__ b_mlp,  // [16]
    const float* __restrict__ W_out,  // [16,256]
    const float* __restrict__ b_out,  // [256]
    int* __restrict__ out)            // [B,8] int32
{
#pragma clang fp contract(off)
    __shared__ float sWin[DM * H];    // [k][j] row-major
    __shared__ float sEmb[NB * H];    // [bin][i]
    __shared__ float sWmlpT[H * H];   // transposed [i][k]
    __shared__ float sWoutT[NB * H];  // transposed [j][k]
    __shared__ float sbin[H];
    __shared__ float sbmlp[H];
    __shared__ float sbout[NB];

    for (int i = threadIdx.x; i < DM * H; i += BLOCK) sWin[i] = W_in[i];
    for (int i = threadIdx.x; i < NB * H; i += BLOCK) sEmb[i] = embed[i];
    for (int i = threadIdx.x; i < H * H; i += BLOCK) {
        int k = i / H, j = i % H;
        sWmlpT[j * H + k] = W_mlp[i];
    }
    for (int i = threadIdx.x; i < H * NB; i += BLOCK) {
        int k = i / NB, j = i % NB;
        sWoutT[j * H + k] = W_out[i];
    }
    for (int i = threadIdx.x; i < H; i += BLOCK) {
        sbin[i]  = b_in[i];
        sbmlp[i] = b_mlp[i];
    }
    for (int i = threadIdx.x; i < NB; i += BLOCK) sbout[i] = b_out[i];
    __syncthreads();

    const int row = blockIdx.x * BLOCK + threadIdx.x;

    // ---- h = x @ W_in + b_in : mul rounded, then add; k ascending ----
    float h[H];
#pragma unroll
    for (int j = 0; j < H; ++j) h[j] = 0.0f;

    const float4* xr = reinterpret_cast<const float4*>(x + (size_t)row * DM);
    for (int k4 = 0; k4 < DM / 4; ++k4) {
        float4 v = xr[k4];
        const float* w0 = &sWin[(k4 * 4 + 0) * H];
        const float* w1 = &sWin[(k4 * 4 + 1) * H];
        const float* w2 = &sWin[(k4 * 4 + 2) * H];
        const float* w3 = &sWin[(k4 * 4 + 3) * H];
#pragma unroll
        for (int j = 0; j < H; ++j) {
            float a = h[j];
            a = a + v.x * w0[j];   // separate mul + add (contract off)
            a = a + v.y * w1[j];
            a = a + v.z * w2[j];
            a = a + v.w * w3[j];
            h[j] = a;
        }
    }
#pragma unroll
    for (int j = 0; j < H; ++j) h[j] = h[j] + sbin[j];

    int bins_[DEPTHN];

    for (int d = 0; d < DEPTHN; ++d) {
        // ---- logits = h @ W_out + b_out ; argmax (first-index ties) ----
        float best = -INFINITY;
        int bi = 0;
        for (int j = 0; j < NB; ++j) {
            const float* wr = &sWoutT[j * H];
            float acc = 0.0f;
#pragma unroll
            for (int i = 0; i < H; ++i) acc = acc + h[i] * wr[i];
            acc = acc + sbout[j];
            if (acc > best) { best = acc; bi = j; }
        }
        bins_[d] = bi;

        // ---- h = h + embed[bi] ----
        const float* er = &sEmb[bi * H];
#pragma unroll
        for (int i = 0; i < H; ++i) h[i] = h[i] + er[i];

        // ---- z = h @ W_mlp + b_mlp ; h = z * (1/(1+np_exp(-z))) ----
        float hn[H];
#pragma unroll
        for (int i = 0; i < H; ++i) {
            const float* wr = &sWmlpT[i * H];
            float acc = 0.0f;
#pragma unroll
            for (int k = 0; k < H; ++k) acc = acc + h[k] * wr[k];
            acc = acc + sbmlp[i];
            float e = np_expf(-acc);
            float s = 1.0f / (1.0f + e);
            hn[i] = acc * s;
        }
#pragma unroll
        for (int i = 0; i < H; ++i) h[i] = hn[i];
    }

    int4* o = reinterpret_cast<int4*>(out + (size_t)row * DEPTHN);
    o[0] = make_int4(bins_[0], bins_[1], bins_[2], bins_[3]);
    o[1] = make_int4(bins_[4], bins_[5], bins_[6], bins_[7]);
}

extern "C" void kernel_launch(void* const* d_in, const int* in_sizes, int n_in,
                              void* d_out, int out_size, void* d_ws, size_t ws_size,
                              hipStream_t stream) {
    const float* x     = (const float*)d_in[0];
    const float* W_in  = (const float*)d_in[1];
    const float* b_in  = (const float*)d_in[2];
    const float* embed = (const float*)d_in[3];
    const float* W_mlp = (const float*)d_in[4];
    const float* b_mlp = (const float*)d_in[5];
    const float* W_out = (const float*)d_in[6];
    const float* b_out = (const float*)d_in[7];
    int* out = (int*)d_out;

    dim3 grid(BATCH / BLOCK);   // 1024 blocks
    dim3 block(BLOCK);
    addrnet_nofma_kernel<<<grid, block, 0, stream>>>(x, W_in, b_in, embed,
                                                     W_mlp, b_mlp, W_out, b_out,
                                                     out);
}

// Round 5
// 1313.933 us; speedup vs baseline: 1.3648x; 1.3648x over previous
//
#include <hip/hip_runtime.h>
#include <math.h>

// AddrNet eval forward: B=524288, D_MODEL=128, HID=16, N_BINS=256, DEPTH=8.
// Round 5: same bit-exact arithmetic contract as the PASSING Round-4 kernel
// (no-FMA separate mul/add roundings, k-ascending sums, bias-after, np-Cephes
// exp, mul-form silu, strict-> argmax). Optimization is mapping-only:
//   - R=2 rows per thread: every wave-uniform W broadcast read from LDS is
//     amortized over 2 rows (halves LDS inst count per row).
//   - explicit float4 (ds_read_b128) weight reads, unroll-4 bin loop.
//   - bins stored straight to global per depth (no index array -> no scratch).
//   - __launch_bounds__(512,4): VGPR<=128 -> 4 waves/SIMD; 512 blocks = 2/CU.

constexpr int BATCH  = 524288;
constexpr int DM     = 128;
constexpr int H      = 16;
constexpr int NB     = 256;
constexpr int DEPTHN = 8;

constexpr int BLOCK = 512;
constexpr int R     = 2;                    // rows per thread

__device__ __forceinline__ float np_expf(float x) {
    // Replica of numpy's SIMD float32 exp (Cephes scheme). Explicit FMAs:
    // unaffected by fp-contract settings. MUST stay bit-identical to R4.
    const float LOG2E = 1.442695040888963407f;
    const float C1    = 0.693359375f;
    const float C2    = -2.12194440e-4f;
    float q = rintf(x * LOG2E);
    float r = __builtin_fmaf(q, -C1, x);
    r = __builtin_fmaf(q, -C2, r);
    float p = 1.9875691500E-4f;
    p = __builtin_fmaf(p, r, 1.3981999507E-3f);
    p = __builtin_fmaf(p, r, 8.3334519073E-3f);
    p = __builtin_fmaf(p, r, 4.1665795894E-2f);
    p = __builtin_fmaf(p, r, 1.6666665459E-1f);
    p = __builtin_fmaf(p, r, 5.0000001201E-1f);
    p = __builtin_fmaf(p, r * r, r);
    p = p + 1.0f;
    if (x > 88.72283935546875f)      return INFINITY;
    if (x < -103.97208404541015625f) return 0.0f;
    return ldexpf(p, (int)q);
}

__global__ __launch_bounds__(BLOCK, 4) void addrnet_r2_kernel(
    const float* __restrict__ x,      // [B,128]
    const float* __restrict__ W_in,   // [128,16]
    const float* __restrict__ b_in,   // [16]
    const float* __restrict__ embed,  // [256,16]
    const float* __restrict__ W_mlp,  // [16,16]
    const float* __restrict__ b_mlp,  // [16]
    const float* __restrict__ W_out,  // [16,256]
    const float* __restrict__ b_out,  // [256]
    int* __restrict__ out)            // [B,8] int32
{
#pragma clang fp contract(off)
    __shared__ __align__(16) float sWin[DM * H];    // [k][j] row-major
    __shared__ __align__(16) float sEmb[NB * H];    // [bin][i]
    __shared__ __align__(16) float sWmlpT[H * H];   // transposed [i][k]
    __shared__ __align__(16) float sWoutT[NB * H];  // transposed [j][k]
    __shared__ float sbin[H];
    __shared__ float sbmlp[H];
    __shared__ float sbout[NB];

    for (int i = threadIdx.x; i < DM * H; i += BLOCK) sWin[i] = W_in[i];
    for (int i = threadIdx.x; i < NB * H; i += BLOCK) sEmb[i] = embed[i];
    for (int i = threadIdx.x; i < H * H; i += BLOCK) {
        int k = i / H, j = i % H;
        sWmlpT[j * H + k] = W_mlp[i];
    }
    for (int i = threadIdx.x; i < H * NB; i += BLOCK) {
        int k = i / NB, j = i % NB;
        sWoutT[j * H + k] = W_out[i];
    }
    for (int i = threadIdx.x; i < H; i += BLOCK) {
        sbin[i]  = b_in[i];
        sbmlp[i] = b_mlp[i];
    }
    for (int i = threadIdx.x; i < NB; i += BLOCK) sbout[i] = b_out[i];
    __syncthreads();

    const int row0 = blockIdx.x * (BLOCK * R) + threadIdx.x;
    const int row1 = row0 + BLOCK;

    // ---- h = x @ W_in + b_in : mul rounded, then add; k ascending ----
    float h0[H], h1[H];
#pragma unroll
    for (int j = 0; j < H; ++j) { h0[j] = 0.0f; h1[j] = 0.0f; }

    const float4* xr0 = reinterpret_cast<const float4*>(x + (size_t)row0 * DM);
    const float4* xr1 = reinterpret_cast<const float4*>(x + (size_t)row1 * DM);
    for (int k4 = 0; k4 < DM / 4; ++k4) {
        float4 v0 = xr0[k4];
        float4 v1 = xr1[k4];
        const float* w0 = &sWin[(k4 * 4 + 0) * H];
        const float* w1 = &sWin[(k4 * 4 + 1) * H];
        const float* w2 = &sWin[(k4 * 4 + 2) * H];
        const float* w3 = &sWin[(k4 * 4 + 3) * H];
#pragma unroll
        for (int j = 0; j < H; ++j) {
            float a = h0[j];
            a = a + v0.x * w0[j];
            a = a + v0.y * w1[j];
            a = a + v0.z * w2[j];
            a = a + v0.w * w3[j];
            h0[j] = a;
            float b = h1[j];
            b = b + v1.x * w0[j];
            b = b + v1.y * w1[j];
            b = b + v1.z * w2[j];
            b = b + v1.w * w3[j];
            h1[j] = b;
        }
    }
#pragma unroll
    for (int j = 0; j < H; ++j) {
        h0[j] = h0[j] + sbin[j];
        h1[j] = h1[j] + sbin[j];
    }

    int* o0 = out + (size_t)row0 * DEPTHN;
    int* o1 = out + (size_t)row1 * DEPTHN;

    for (int d = 0; d < DEPTHN; ++d) {
        // ---- logits = h @ W_out + b_out ; argmax (first-index ties) ----
        float best0 = -INFINITY, best1 = -INFINITY;
        int bi0 = 0, bi1 = 0;
#pragma unroll 4
        for (int j = 0; j < NB; ++j) {
            const float4* w4 = reinterpret_cast<const float4*>(&sWoutT[j * H]);
            float4 wa = w4[0], wb = w4[1], wc = w4[2], wd = w4[3];
            const float w[16] = {wa.x, wa.y, wa.z, wa.w, wb.x, wb.y, wb.z, wb.w,
                                 wc.x, wc.y, wc.z, wc.w, wd.x, wd.y, wd.z, wd.w};
            float a0 = 0.0f, a1 = 0.0f;
#pragma unroll
            for (int k = 0; k < H; ++k) a0 = a0 + h0[k] * w[k];
#pragma unroll
            for (int k = 0; k < H; ++k) a1 = a1 + h1[k] * w[k];
            float bj = sbout[j];
            a0 = a0 + bj;
            a1 = a1 + bj;
            bool c0 = a0 > best0;
            bi0   = c0 ? j  : bi0;
            best0 = c0 ? a0 : best0;
            bool c1 = a1 > best1;
            bi1   = c1 ? j  : bi1;
            best1 = c1 ? a1 : best1;
        }
        o0[d] = bi0;
        o1[d] = bi1;

        // ---- h = h + embed[bi] ----
        {
            const float4* e0 = reinterpret_cast<const float4*>(&sEmb[bi0 * H]);
            const float4* e1 = reinterpret_cast<const float4*>(&sEmb[bi1 * H]);
            float4 ea = e0[0], eb = e0[1], ec = e0[2], ed = e0[3];
            const float e0w[16] = {ea.x, ea.y, ea.z, ea.w, eb.x, eb.y, eb.z, eb.w,
                                   ec.x, ec.y, ec.z, ec.w, ed.x, ed.y, ed.z, ed.w};
            float4 fa = e1[0], fb = e1[1], fc = e1[2], fd = e1[3];
            const float e1w[16] = {fa.x, fa.y, fa.z, fa.w, fb.x, fb.y, fb.z, fb.w,
                                   fc.x, fc.y, fc.z, fc.w, fd.x, fd.y, fd.z, fd.w};
#pragma unroll
            for (int i = 0; i < H; ++i) {
                h0[i] = h0[i] + e0w[i];
                h1[i] = h1[i] + e1w[i];
            }
        }

        // ---- z = h @ W_mlp + b_mlp ; h = z * (1/(1+np_exp(-z))) ----
        float hn0[H], hn1[H];
#pragma unroll
        for (int i = 0; i < H; ++i) {
            const float4* w4 = reinterpret_cast<const float4*>(&sWmlpT[i * H]);
            float4 wa = w4[0], wb = w4[1], wc = w4[2], wd = w4[3];
            const float w[16] = {wa.x, wa.y, wa.z, wa.w, wb.x, wb.y, wb.z, wb.w,
                                 wc.x, wc.y, wc.z, wc.w, wd.x, wd.y, wd.z, wd.w};
            float a0 = 0.0f, a1 = 0.0f;
#pragma unroll
            for (int k = 0; k < H; ++k) a0 = a0 + h0[k] * w[k];
#pragma unroll
            for (int k = 0; k < H; ++k) a1 = a1 + h1[k] * w[k];
            float bm = sbmlp[i];
            a0 = a0 + bm;
            a1 = a1 + bm;
            float e0v = np_expf(-a0);
            float s0  = 1.0f / (1.0f + e0v);
            hn0[i] = a0 * s0;
            float e1v = np_expf(-a1);
            float s1  = 1.0f / (1.0f + e1v);
            hn1[i] = a1 * s1;
        }
#pragma unroll
        for (int i = 0; i < H; ++i) { h0[i] = hn0[i]; h1[i] = hn1[i]; }
    }
}

extern "C" void kernel_launch(void* const* d_in, const int* in_sizes, int n_in,
                              void* d_out, int out_size, void* d_ws, size_t ws_size,
                              hipStream_t stream) {
    const float* x     = (const float*)d_in[0];
    const float* W_in  = (const float*)d_in[1];
    const float* b_in  = (const float*)d_in[2];
    const float* embed = (const float*)d_in[3];
    const float* W_mlp = (const float*)d_in[4];
    const float* b_mlp = (const float*)d_in[5];
    const float* W_out = (const float*)d_in[6];
    const float* b_out = (const float*)d_in[7];
    int* out = (int*)d_out;

    dim3 grid(BATCH / (BLOCK * R));   // 512 blocks, exactly 2 per CU
    dim3 block(BLOCK);
    addrnet_r2_kernel<<<grid, block, 0, stream>>>(x, W_in, b_in, embed, W_mlp,
                                                  b_mlp, W_out, b_out, out);
}

// Round 6
// 1294.115 us; speedup vs baseline: 1.3857x; 1.0153x over previous
//
#include <hip/hip_runtime.h>
#include <math.h>

// AddrNet eval forward: B=524288, D_MODEL=128, HID=16, N_BINS=256, DEPTH=8.
// Round 6: same bit-exact arithmetic contract as PASSING R4/R5 (no-FMA
// separate mul/add roundings, k-ascending sums, bias-after, np-Cephes exp,
// mul-form silu, strict-> argmax). Mapping changes only:
//   - BLOCK=256, __launch_bounds__(256,4): unambiguous 128-VGPR cap ->
//     no scratch spill (R5's VGPR=64 cap caused ~1.8 GB spill traffic).
//   - W_in/b_in read from global with wave-uniform addresses (scalarizes to
//     s_load; bit-identical values) -> LDS down to ~34 KB -> 4 blocks/CU,
//     matching the 16-waves/CU VGPR occupancy target.
//   - R=2 rows/thread retained (weight broadcasts amortized over 2 rows).

constexpr int BATCH  = 524288;
constexpr int DM     = 128;
constexpr int H      = 16;
constexpr int NB     = 256;
constexpr int DEPTHN = 8;

constexpr int BLOCK = 256;
constexpr int R     = 2;                    // rows per thread

__device__ __forceinline__ float np_expf(float x) {
    // Replica of numpy's SIMD float32 exp (Cephes scheme). Explicit FMAs:
    // unaffected by fp-contract settings. MUST stay bit-identical to R4.
    const float LOG2E = 1.442695040888963407f;
    const float C1    = 0.693359375f;
    const float C2    = -2.12194440e-4f;
    float q = rintf(x * LOG2E);
    float r = __builtin_fmaf(q, -C1, x);
    r = __builtin_fmaf(q, -C2, r);
    float p = 1.9875691500E-4f;
    p = __builtin_fmaf(p, r, 1.3981999507E-3f);
    p = __builtin_fmaf(p, r, 8.3334519073E-3f);
    p = __builtin_fmaf(p, r, 4.1665795894E-2f);
    p = __builtin_fmaf(p, r, 1.6666665459E-1f);
    p = __builtin_fmaf(p, r, 5.0000001201E-1f);
    p = __builtin_fmaf(p, r * r, r);
    p = p + 1.0f;
    if (x > 88.72283935546875f)      return INFINITY;
    if (x < -103.97208404541015625f) return 0.0f;
    return ldexpf(p, (int)q);
}

__global__ __launch_bounds__(BLOCK, 4) void addrnet_r6_kernel(
    const float* __restrict__ x,      // [B,128]
    const float* __restrict__ W_in,   // [128,16]
    const float* __restrict__ b_in,   // [16]
    const float* __restrict__ embed,  // [256,16]
    const float* __restrict__ W_mlp,  // [16,16]
    const float* __restrict__ b_mlp,  // [16]
    const float* __restrict__ W_out,  // [16,256]
    const float* __restrict__ b_out,  // [256]
    int* __restrict__ out)            // [B,8] int32
{
#pragma clang fp contract(off)
    __shared__ __align__(16) float sEmb[NB * H];    // [bin][i]       16 KB
    __shared__ __align__(16) float sWoutT[NB * H];  // [j][k]         16 KB
    __shared__ __align__(16) float sWmlpT[H * H];   // [i][k]          1 KB
    __shared__ float sbmlp[H];
    __shared__ float sbout[NB];                     //                 1 KB

    for (int i = threadIdx.x; i < NB * H; i += BLOCK) sEmb[i] = embed[i];
    for (int i = threadIdx.x; i < H * NB; i += BLOCK) {
        int k = i / NB, j = i % NB;               // W_out[k][j] -> sWoutT[j][k]
        sWoutT[j * H + k] = W_out[i];
    }
    for (int i = threadIdx.x; i < H * H; i += BLOCK) {
        int k = i / H, j = i % H;                 // W_mlp[k][j] -> sWmlpT[j][k]
        sWmlpT[j * H + k] = W_mlp[i];
    }
    for (int i = threadIdx.x; i < H; i += BLOCK) sbmlp[i] = b_mlp[i];
    for (int i = threadIdx.x; i < NB; i += BLOCK) sbout[i] = b_out[i];
    __syncthreads();

    const int row0 = blockIdx.x * (BLOCK * R) + threadIdx.x;
    const int row1 = row0 + BLOCK;

    // ---- h = x @ W_in + b_in : mul rounded, then add; k ascending.
    //      W_in rows read wave-uniform from global (s_load path). ----
    float h0[H], h1[H];
#pragma unroll
    for (int j = 0; j < H; ++j) { h0[j] = 0.0f; h1[j] = 0.0f; }

    const float4* xr0 = reinterpret_cast<const float4*>(x + (size_t)row0 * DM);
    const float4* xr1 = reinterpret_cast<const float4*>(x + (size_t)row1 * DM);
    for (int k4 = 0; k4 < DM / 4; ++k4) {
        float4 v0 = xr0[k4];
        float4 v1 = xr1[k4];
        const float* w0 = &W_in[(k4 * 4 + 0) * H];
        const float* w1 = &W_in[(k4 * 4 + 1) * H];
        const float* w2 = &W_in[(k4 * 4 + 2) * H];
        const float* w3 = &W_in[(k4 * 4 + 3) * H];
#pragma unroll
        for (int j = 0; j < H; ++j) {
            float a = h0[j];
            a = a + v0.x * w0[j];
            a = a + v0.y * w1[j];
            a = a + v0.z * w2[j];
            a = a + v0.w * w3[j];
            h0[j] = a;
            float b = h1[j];
            b = b + v1.x * w0[j];
            b = b + v1.y * w1[j];
            b = b + v1.z * w2[j];
            b = b + v1.w * w3[j];
            h1[j] = b;
        }
    }
#pragma unroll
    for (int j = 0; j < H; ++j) {
        float bj = b_in[j];          // uniform global (s_load)
        h0[j] = h0[j] + bj;
        h1[j] = h1[j] + bj;
    }

    int* o0 = out + (size_t)row0 * DEPTHN;
    int* o1 = out + (size_t)row1 * DEPTHN;

    for (int d = 0; d < DEPTHN; ++d) {
        // ---- logits = h @ W_out + b_out ; argmax (first-index ties) ----
        float best0 = -INFINITY, best1 = -INFINITY;
        int bi0 = 0, bi1 = 0;
#pragma unroll 4
        for (int j = 0; j < NB; ++j) {
            const float4* w4 = reinterpret_cast<const float4*>(&sWoutT[j * H]);
            float4 wa = w4[0], wb = w4[1], wc = w4[2], wd = w4[3];
            const float w[16] = {wa.x, wa.y, wa.z, wa.w, wb.x, wb.y, wb.z, wb.w,
                                 wc.x, wc.y, wc.z, wc.w, wd.x, wd.y, wd.z, wd.w};
            float a0 = 0.0f, a1 = 0.0f;
#pragma unroll
            for (int k = 0; k < H; ++k) a0 = a0 + h0[k] * w[k];
#pragma unroll
            for (int k = 0; k < H; ++k) a1 = a1 + h1[k] * w[k];
            float bj = sbout[j];
            a0 = a0 + bj;
            a1 = a1 + bj;
            bool c0 = a0 > best0;
            bi0   = c0 ? j  : bi0;
            best0 = c0 ? a0 : best0;
            bool c1 = a1 > best1;
            bi1   = c1 ? j  : bi1;
            best1 = c1 ? a1 : best1;
        }
        o0[d] = bi0;
        o1[d] = bi1;

        // ---- h = h + embed[bi] ----
        {
            const float4* e0 = reinterpret_cast<const float4*>(&sEmb[bi0 * H]);
            const float4* e1 = reinterpret_cast<const float4*>(&sEmb[bi1 * H]);
            float4 ea = e0[0], eb = e0[1], ec = e0[2], ed = e0[3];
            const float e0w[16] = {ea.x, ea.y, ea.z, ea.w, eb.x, eb.y, eb.z, eb.w,
                                   ec.x, ec.y, ec.z, ec.w, ed.x, ed.y, ed.z, ed.w};
            float4 fa = e1[0], fb = e1[1], fc = e1[2], fd = e1[3];
            const float e1w[16] = {fa.x, fa.y, fa.z, fa.w, fb.x, fb.y, fb.z, fb.w,
                                   fc.x, fc.y, fc.z, fc.w, fd.x, fd.y, fd.z, fd.w};
#pragma unroll
            for (int i = 0; i < H; ++i) {
                h0[i] = h0[i] + e0w[i];
                h1[i] = h1[i] + e1w[i];
            }
        }

        // ---- z = h @ W_mlp + b_mlp ; h = z * (1/(1+np_exp(-z))) ----
        float hn0[H], hn1[H];
#pragma unroll
        for (int i = 0; i < H; ++i) {
            const float4* w4 = reinterpret_cast<const float4*>(&sWmlpT[i * H]);
            float4 wa = w4[0], wb = w4[1], wc = w4[2], wd = w4[3];
            const float w[16] = {wa.x, wa.y, wa.z, wa.w, wb.x, wb.y, wb.z, wb.w,
                                 wc.x, wc.y, wc.z, wc.w, wd.x, wd.y, wd.z, wd.w};
            float a0 = 0.0f, a1 = 0.0f;
#pragma unroll
            for (int k = 0; k < H; ++k) a0 = a0 + h0[k] * w[k];
#pragma unroll
            for (int k = 0; k < H; ++k) a1 = a1 + h1[k] * w[k];
            float bm = sbmlp[i];
            a0 = a0 + bm;
            a1 = a1 + bm;
            float e0v = np_expf(-a0);
            float s0  = 1.0f / (1.0f + e0v);
            hn0[i] = a0 * s0;
            float e1v = np_expf(-a1);
            float s1  = 1.0f / (1.0f + e1v);
            hn1[i] = a1 * s1;
        }
#pragma unroll
        for (int i = 0; i < H; ++i) { h0[i] = hn0[i]; h1[i] = hn1[i]; }
    }
}

extern "C" void kernel_launch(void* const* d_in, const int* in_sizes, int n_in,
                              void* d_out, int out_size, void* d_ws, size_t ws_size,
                              hipStream_t stream) {
    const float* x     = (const float*)d_in[0];
    const float* W_in  = (const float*)d_in[1];
    const float* b_in  = (const float*)d_in[2];
    const float* embed = (const float*)d_in[3];
    const float* W_mlp = (const float*)d_in[4];
    const float* b_mlp = (const float*)d_in[5];
    const float* W_out = (const float*)d_in[6];
    const float* b_out = (const float*)d_in[7];
    int* out = (int*)d_out;

    dim3 grid(BATCH / (BLOCK * R));   // 1024 blocks
    dim3 block(BLOCK);
    addrnet_r6_kernel<<<grid, block, 0, stream>>>(x, W_in, b_in, embed, W_mlp,
                                                  b_mlp, W_out, b_out, out);
}